// Round 4
// baseline (327.156 us; speedup 1.0000x reference)
//
#include <hip/hip_runtime.h>
#include <hip/hip_fp16.h>

#define NSTEPS 30
#define DIM 192
static constexpr long DHW = (long)DIM * DIM * DIM;
static constexpr int PTS_PER_WAVE = 21;   // fallback kernel only

// Unrolled cofactor 4x4 inverse in double — registers only, no scratch.
__global__ void invert4x4_kernel(const float* __restrict__ aff,
                                 float* __restrict__ out, int B) {
    int b = blockIdx.x * blockDim.x + threadIdx.x;
    if (b >= B) return;
    double a[16];
#pragma unroll
    for (int i = 0; i < 16; i++) a[i] = (double)aff[b * 16 + i];
    double s0 = a[0]*a[5]  - a[4]*a[1];
    double s1 = a[0]*a[6]  - a[4]*a[2];
    double s2 = a[0]*a[7]  - a[4]*a[3];
    double s3 = a[1]*a[6]  - a[5]*a[2];
    double s4 = a[1]*a[7]  - a[5]*a[3];
    double s5 = a[2]*a[7]  - a[6]*a[3];
    double c5 = a[10]*a[15] - a[14]*a[11];
    double c4 = a[9]*a[15]  - a[13]*a[11];
    double c3 = a[9]*a[14]  - a[13]*a[10];
    double c2 = a[8]*a[15]  - a[12]*a[11];
    double c1 = a[8]*a[14]  - a[12]*a[10];
    double c0 = a[8]*a[13]  - a[12]*a[9];
    double det = s0*c5 - s1*c4 + s2*c3 + s3*c2 - s4*c1 + s5*c0;
    double inv = 1.0 / det;
    double o[16];
    o[0]  = ( a[5]*c5 - a[6]*c4 + a[7]*c3) * inv;
    o[1]  = (-a[1]*c5 + a[2]*c4 - a[3]*c3) * inv;
    o[2]  = ( a[13]*s5 - a[14]*s4 + a[15]*s3) * inv;
    o[3]  = (-a[9]*s5 + a[10]*s4 - a[11]*s3) * inv;
    o[4]  = (-a[4]*c5 + a[6]*c2 - a[7]*c1) * inv;
    o[5]  = ( a[0]*c5 - a[2]*c2 + a[3]*c1) * inv;
    o[6]  = (-a[12]*s5 + a[14]*s2 - a[15]*s1) * inv;
    o[7]  = ( a[8]*s5 - a[10]*s2 + a[11]*s1) * inv;
    o[8]  = ( a[4]*c4 - a[5]*c2 + a[7]*c0) * inv;
    o[9]  = (-a[0]*c4 + a[1]*c2 - a[3]*c0) * inv;
    o[10] = ( a[12]*s4 - a[13]*s2 + a[15]*s0) * inv;
    o[11] = (-a[8]*s4 + a[9]*s2 - a[11]*s0) * inv;
    o[12] = (-a[4]*c3 + a[5]*c1 - a[6]*c0) * inv;
    o[13] = ( a[0]*c3 - a[1]*c1 + a[2]*c0) * inv;
    o[14] = (-a[12]*s3 + a[13]*s1 - a[14]*s0) * inv;
    o[15] = ( a[8]*s3 - a[9]*s1 + a[10]*s0) * inv;
#pragma unroll
    for (int i = 0; i < 16; i++) out[b * 16 + i] = (float)o[i];
}

// Repack flow (B,3,D,H,W) f32 -> (B,D,H,W,4) fp16, 4 voxels/thread vectorized.
__global__ __launch_bounds__(256) void repack4_kernel(const float* __restrict__ flow,
                                                      __half* __restrict__ packed) {
    long q = (long)blockIdx.x * blockDim.x + threadIdx.x;   // quad index
    int b = blockIdx.y;
    long v0 = q * 4;
    if (v0 >= DHW) return;
    const float* F = flow + (size_t)b * 3 * DHW;
    float4 f0 = *reinterpret_cast<const float4*>(F + v0);            // ch0 x4
    float4 f1 = *reinterpret_cast<const float4*>(F + v0 + DHW);      // ch1 x4
    float4 f2 = *reinterpret_cast<const float4*>(F + v0 + 2 * DHW);  // ch2 x4
    union { __half2 h[2]; int2 i2; } u;
    int4 o0, o1;
    u.h[0] = __floats2half2_rn(f0.x, f1.x); u.h[1] = __floats2half2_rn(f2.x, 0.f);
    o0.x = u.i2.x; o0.y = u.i2.y;
    u.h[0] = __floats2half2_rn(f0.y, f1.y); u.h[1] = __floats2half2_rn(f2.y, 0.f);
    o0.z = u.i2.x; o0.w = u.i2.y;
    u.h[0] = __floats2half2_rn(f0.z, f1.z); u.h[1] = __floats2half2_rn(f2.z, 0.f);
    o1.x = u.i2.x; o1.y = u.i2.y;
    u.h[0] = __floats2half2_rn(f0.w, f1.w); u.h[1] = __floats2half2_rn(f2.w, 0.f);
    o1.z = u.i2.x; o1.w = u.i2.y;
    int4* out = reinterpret_cast<int4*>(packed) + (((size_t)b * DHW + v0) >> 1);
    out[0] = o0;
    out[1] = o1;
}

static __device__ __forceinline__ float2 h2f(unsigned u) {
    return __half22float2(__builtin_bit_cast(__half2, u));
}

// 1 lane per point. Refill = 4 x 16B loads (both w-corners x 3ch per (d,h) row).
__global__ __launch_bounds__(256) void deform1_kernel(
    const float* __restrict__ verts,
    const float* __restrict__ affine,
    const __half* __restrict__ packed,
    const float* __restrict__ invaff,
    float* __restrict__ out_pred,
    float* __restrict__ out_flow,
    int N, int B) {
    int idx = blockIdx.x * blockDim.x + threadIdx.x;
    int total = B * N;
    bool valid = idx < total;
    int i = valid ? idx : total - 1;
    int b = i / N;
    int n = i - b * N;

    const float* A = affine + b * 16;
    const float* v = verts + (size_t)i * 3;
    float vx = v[0], vy = v[1], vz = v[2];
    float x = A[0] * vx + A[1] * vy + A[2]  * vz + A[3];
    float y = A[4] * vx + A[5] * vy + A[6]  * vz + A[7];
    float z = A[8] * vx + A[9] * vy + A[10] * vz + A[11];
    const float px = x, py = y, pz = z;

    const char* Pb = (const char*)(packed + (size_t)b * DHW * 4);
    const float scale = (float)(1.0 / NSTEPS);

    float cc[3][8];   // [ch][row*2 + corner], rows: 00,01,10,11 (d,h)
    int key = -1;

    for (int s = 0; s < NSTEPS; s++) {
        float pd = fminf(fmaxf(x, 0.0f), (float)(DIM - 1));
        float ph = fminf(fmaxf(y, 0.0f), (float)(DIM - 1));
        float pw = fminf(fmaxf(z, 0.0f), (float)(DIM - 1));
        float fd0 = floorf(pd), fh0 = floorf(ph), fw0 = floorf(pw);
        int d0 = (int)fd0, h0 = (int)fh0, w0 = (int)fw0;
        float fd = pd - fd0, fh = ph - fh0, fw = pw - fw0;

        int k = (d0 * DIM + h0) * DIM + w0;
        if (k != key) {
            key = k;
            int d1 = min(d0 + 1, DIM - 1);
            int h1 = min(h0 + 1, DIM - 1);
            int lb = min(w0, DIM - 2);    // load pair (lb, lb+1)
            int sel = w0 - lb;            // 1 only when w0==191 (fw==0 there)
            int rr[4];
            rr[0] = (d0 * DIM + h0) * DIM;
            rr[1] = (d0 * DIM + h1) * DIM;
            rr[2] = (d1 * DIM + h0) * DIM;
            rr[3] = (d1 * DIM + h1) * DIM;
#pragma unroll
            for (int r = 0; r < 4; r++) {
                const uint2* p = reinterpret_cast<const uint2*>(
                    Pb + (size_t)(rr[r] + lb) * 8);
                uint2 qa = p[0];          // voxel lb:   (c0,c1),(c2,pad)
                uint2 qb = p[1];          // voxel lb+1: (c0,c1),(c2,pad)
                float2 a01 = h2f(qa.x), a2_ = h2f(qa.y);
                float2 b01 = h2f(qb.x), b2_ = h2f(qb.y);
                float c0a = sel ? b01.x : a01.x;
                float c1a = sel ? b01.y : a01.y;
                float c2a = sel ? b2_.x : a2_.x;
                cc[0][2*r+0] = c0a  * scale; cc[0][2*r+1] = b01.x * scale;
                cc[1][2*r+0] = c1a  * scale; cc[1][2*r+1] = b01.y * scale;
                cc[2][2*r+0] = c2a  * scale; cc[2][2*r+1] = b2_.x * scale;
            }
        }

        float omfw = 1.0f - fw, omfh = 1.0f - fh, omfd = 1.0f - fd;
        float vals[3];
#pragma unroll
        for (int c = 0; c < 3; c++) {
            float c00 = cc[c][0] * omfw + cc[c][1] * fw;
            float c01 = cc[c][2] * omfw + cc[c][3] * fw;
            float c10 = cc[c][4] * omfw + cc[c][5] * fw;
            float c11 = cc[c][6] * omfw + cc[c][7] * fw;
            float c0 = c00 * omfh + c01 * fh;
            float c1 = c10 * omfh + c11 * fh;
            vals[c] = c0 * omfd + c1 * fd;
        }
        x += vals[0];
        y += vals[1];
        z += vals[2];
    }

    if (valid) {
        float fx = x - px, fy = y - py, fz = z - pz;
        const float* Ai = invaff + b * 16;
        float ox = Ai[0] * x + Ai[1] * y + Ai[2]  * z + Ai[3];
        float oy = Ai[4] * x + Ai[5] * y + Ai[6]  * z + Ai[7];
        float oz = Ai[8] * x + Ai[9] * y + Ai[10] * z + Ai[11];
        size_t po = (size_t)i * 3;
        out_pred[po + 0] = ox;
        out_pred[po + 1] = oy;
        out_pred[po + 2] = oz;
        size_t fo = (size_t)b * 3 * N + n;
        out_flow[fo]         = fx;
        out_flow[fo + N]     = fy;
        out_flow[fo + 2 * N] = fz;
    }
}

// Fallback: f32 direct-gather (3 lanes/point) if ws can't hold the packed volume.
__global__ __launch_bounds__(256) void deform_kernel(
    const float* __restrict__ verts,
    const float* __restrict__ affine,
    const float* __restrict__ flow,
    const float* __restrict__ invaff,
    float* __restrict__ out_pred,
    float* __restrict__ out_flow,
    int N, int B) {
    int lane = threadIdx.x & 63;
    int wib  = threadIdx.x >> 6;
    long gwave = (long)blockIdx.x * (blockDim.x >> 6) + wib;
    int piw = lane / 3;
    if (piw > PTS_PER_WAVE - 1) piw = PTS_PER_WAVE - 1;
    int ch = lane - piw * 3;
    if (ch > 2) ch = 2;
    long pt = gwave * PTS_PER_WAVE + piw;
    bool valid = (lane < 63) && (pt < (long)B * N);
    long ptc = valid ? pt : ((long)B * N - 1);
    int b = (int)(ptc / N);
    int n = (int)(ptc - (long)b * N);
    const float* A = affine + b * 16;
    const float* v = verts + (size_t)ptc * 3;
    float vx = v[0], vy = v[1], vz = v[2];
    float x = A[0] * vx + A[1] * vy + A[2]  * vz + A[3];
    float y = A[4] * vx + A[5] * vy + A[6]  * vz + A[7];
    float z = A[8] * vx + A[9] * vy + A[10] * vz + A[11];
    float p0 = (ch == 0) ? x : (ch == 1) ? y : z;
    const float* Fc = flow + ((size_t)b * 3 + ch) * (size_t)DHW;
    const float scale = (float)(1.0 / NSTEPS);
    float cc[8];
    int key = -1;
    int bl = piw * 3;
    for (int s = 0; s < NSTEPS; s++) {
        float pd = fminf(fmaxf(x, 0.0f), (float)(DIM - 1));
        float ph = fminf(fmaxf(y, 0.0f), (float)(DIM - 1));
        float pw = fminf(fmaxf(z, 0.0f), (float)(DIM - 1));
        float fd0 = floorf(pd), fh0 = floorf(ph), fw0 = floorf(pw);
        int d0 = (int)fd0, h0 = (int)fh0, w0 = (int)fw0;
        float fd = pd - fd0, fh = ph - fh0, fw = pw - fw0;
        int k = (d0 * DIM + h0) * DIM + w0;
        if (k != key) {
            key = k;
            int d1 = min(d0 + 1, DIM - 1);
            int h1 = min(h0 + 1, DIM - 1);
            int w1 = min(w0 + 1, DIM - 1);
            int r00 = (d0 * DIM + h0) * DIM;
            int r01 = (d0 * DIM + h1) * DIM;
            int r10 = (d1 * DIM + h0) * DIM;
            int r11 = (d1 * DIM + h1) * DIM;
            cc[0] = Fc[r00 + w0] * scale;
            cc[1] = Fc[r00 + w1] * scale;
            cc[2] = Fc[r01 + w0] * scale;
            cc[3] = Fc[r01 + w1] * scale;
            cc[4] = Fc[r10 + w0] * scale;
            cc[5] = Fc[r10 + w1] * scale;
            cc[6] = Fc[r11 + w0] * scale;
            cc[7] = Fc[r11 + w1] * scale;
        }
        float omfw = 1.0f - fw, omfh = 1.0f - fh, omfd = 1.0f - fd;
        float c00 = cc[0] * omfw + cc[1] * fw;
        float c01 = cc[2] * omfw + cc[3] * fw;
        float c10 = cc[4] * omfw + cc[5] * fw;
        float c11 = cc[6] * omfw + cc[7] * fw;
        float c0 = c00 * omfh + c01 * fh;
        float c1 = c10 * omfh + c11 * fh;
        float val = c0 * omfd + c1 * fd;
        float v0 = __shfl(val, bl,     64);
        float v1 = __shfl(val, bl + 1, 64);
        float v2 = __shfl(val, bl + 2, 64);
        x += v0; y += v1; z += v2;
    }
    if (valid) {
        float posc = (ch == 0) ? x : (ch == 1) ? y : z;
        float fint = posc - p0;
        const float* Ai = invaff + b * 16 + ch * 4;
        float o = Ai[0] * x + Ai[1] * y + Ai[2] * z + Ai[3];
        out_pred[(size_t)ptc * 3 + ch] = o;
        out_flow[(size_t)b * 3 * N + (size_t)ch * N + n] = fint;
    }
}

extern "C" void kernel_launch(void* const* d_in, const int* in_sizes, int n_in,
                              void* d_out, int out_size, void* d_ws, size_t ws_size,
                              hipStream_t stream) {
    const float* verts  = (const float*)d_in[0];
    const float* affine = (const float*)d_in[1];
    const float* flow   = (const float*)d_in[2];

    int B = in_sizes[1] / 16;          // affine is B*4*4
    int N = in_sizes[0] / (3 * B);     // verts is B*N*3

    float* out_pred = (float*)d_out;                      // (B,N,3)
    float* out_flow = out_pred + (size_t)B * N * 3;       // (B,3,N)

    size_t packed_bytes = (size_t)B * DHW * 4 * sizeof(__half);  // 8B/voxel
    bool use_packed = (ws_size >= packed_bytes + 256);

    int total = B * N;

    if (use_packed) {
        __half* packed = (__half*)d_ws;
        float* invaff  = (float*)((char*)d_ws + packed_bytes);
        hipLaunchKernelGGL(invert4x4_kernel, dim3(1), dim3(64), 0, stream,
                           affine, invaff, B);
        long quads = (DHW + 3) / 4;
        long vblocks = (quads + 255) / 256;
        hipLaunchKernelGGL(repack4_kernel, dim3((unsigned)vblocks, B), dim3(256), 0,
                           stream, flow, packed);
        int blocks = (total + 255) / 256;
        hipLaunchKernelGGL(deform1_kernel, dim3(blocks), dim3(256), 0, stream,
                           verts, affine, packed, invaff, out_pred, out_flow, N, B);
    } else {
        float* invaff = (float*)d_ws;
        hipLaunchKernelGGL(invert4x4_kernel, dim3(1), dim3(64), 0, stream,
                           affine, invaff, B);
        long waves  = ((long)total + PTS_PER_WAVE - 1) / PTS_PER_WAVE;
        long blocks = (waves + 3) / 4;
        hipLaunchKernelGGL(deform_kernel, dim3((unsigned)blocks), dim3(256), 0,
                           stream, verts, affine, flow, invaff,
                           out_pred, out_flow, N, B);
    }
}

// Round 5
// 315.645 us; speedup vs baseline: 1.0365x; 1.0365x over previous
//
#include <hip/hip_runtime.h>
#include <hip/hip_fp16.h>

#define NSTEPS 30
#define DIM 192
static constexpr long DHW = (long)DIM * DIM * DIM;
static constexpr int PTS_PER_WAVE = 21;   // fallback kernel only

// Unrolled cofactor 4x4 inverse in double — registers only, no scratch.
__global__ void invert4x4_kernel(const float* __restrict__ aff,
                                 float* __restrict__ out, int B) {
    int b = blockIdx.x * blockDim.x + threadIdx.x;
    if (b >= B) return;
    double a[16];
#pragma unroll
    for (int i = 0; i < 16; i++) a[i] = (double)aff[b * 16 + i];
    double s0 = a[0]*a[5]  - a[4]*a[1];
    double s1 = a[0]*a[6]  - a[4]*a[2];
    double s2 = a[0]*a[7]  - a[4]*a[3];
    double s3 = a[1]*a[6]  - a[5]*a[2];
    double s4 = a[1]*a[7]  - a[5]*a[3];
    double s5 = a[2]*a[7]  - a[6]*a[3];
    double c5 = a[10]*a[15] - a[14]*a[11];
    double c4 = a[9]*a[15]  - a[13]*a[11];
    double c3 = a[9]*a[14]  - a[13]*a[10];
    double c2 = a[8]*a[15]  - a[12]*a[11];
    double c1 = a[8]*a[14]  - a[12]*a[10];
    double c0 = a[8]*a[13]  - a[12]*a[9];
    double det = s0*c5 - s1*c4 + s2*c3 + s3*c2 - s4*c1 + s5*c0;
    double inv = 1.0 / det;
    double o[16];
    o[0]  = ( a[5]*c5 - a[6]*c4 + a[7]*c3) * inv;
    o[1]  = (-a[1]*c5 + a[2]*c4 - a[3]*c3) * inv;
    o[2]  = ( a[13]*s5 - a[14]*s4 + a[15]*s3) * inv;
    o[3]  = (-a[9]*s5 + a[10]*s4 - a[11]*s3) * inv;
    o[4]  = (-a[4]*c5 + a[6]*c2 - a[7]*c1) * inv;
    o[5]  = ( a[0]*c5 - a[2]*c2 + a[3]*c1) * inv;
    o[6]  = (-a[12]*s5 + a[14]*s2 - a[15]*s1) * inv;
    o[7]  = ( a[8]*s5 - a[10]*s2 + a[11]*s1) * inv;
    o[8]  = ( a[4]*c4 - a[5]*c2 + a[7]*c0) * inv;
    o[9]  = (-a[0]*c4 + a[1]*c2 - a[3]*c0) * inv;
    o[10] = ( a[12]*s4 - a[13]*s2 + a[15]*s0) * inv;
    o[11] = (-a[8]*s4 + a[9]*s2 - a[11]*s0) * inv;
    o[12] = (-a[4]*c3 + a[5]*c1 - a[6]*c0) * inv;
    o[13] = ( a[0]*c3 - a[1]*c1 + a[2]*c0) * inv;
    o[14] = (-a[12]*s3 + a[13]*s1 - a[14]*s0) * inv;
    o[15] = ( a[8]*s3 - a[9]*s1 + a[10]*s0) * inv;
#pragma unroll
    for (int i = 0; i < 16; i++) out[b * 16 + i] = (float)o[i];
}

// Repack flow (B,3,D,H,W) f32 -> (B,D,H,W,4) fp16, 4 voxels/thread vectorized.
__global__ __launch_bounds__(256) void repack4_kernel(const float* __restrict__ flow,
                                                      __half* __restrict__ packed) {
    long q = (long)blockIdx.x * blockDim.x + threadIdx.x;   // quad index
    int b = blockIdx.y;
    long v0 = q * 4;
    if (v0 >= DHW) return;
    const float* F = flow + (size_t)b * 3 * DHW;
    float4 f0 = *reinterpret_cast<const float4*>(F + v0);            // ch0 x4
    float4 f1 = *reinterpret_cast<const float4*>(F + v0 + DHW);      // ch1 x4
    float4 f2 = *reinterpret_cast<const float4*>(F + v0 + 2 * DHW);  // ch2 x4
    union { __half2 h[2]; int2 i2; } u;
    int4 o0, o1;
    u.h[0] = __floats2half2_rn(f0.x, f1.x); u.h[1] = __floats2half2_rn(f2.x, 0.f);
    o0.x = u.i2.x; o0.y = u.i2.y;
    u.h[0] = __floats2half2_rn(f0.y, f1.y); u.h[1] = __floats2half2_rn(f2.y, 0.f);
    o0.z = u.i2.x; o0.w = u.i2.y;
    u.h[0] = __floats2half2_rn(f0.z, f1.z); u.h[1] = __floats2half2_rn(f2.z, 0.f);
    o1.x = u.i2.x; o1.y = u.i2.y;
    u.h[0] = __floats2half2_rn(f0.w, f1.w); u.h[1] = __floats2half2_rn(f2.w, 0.f);
    o1.z = u.i2.x; o1.w = u.i2.y;
    int4* out = reinterpret_cast<int4*>(packed) + (((size_t)b * DHW + v0) >> 1);
    out[0] = o0;
    out[1] = o1;
}

static __device__ __forceinline__ float2 h2f(unsigned u) {
    return __half22float2(__builtin_bit_cast(__half2, u));
}

// 4 lanes per point: lane sub owns row (d = sub&2 ? d1:d0, h = sub&1 ? h1:h0).
// Refill = 2 x 8B loads per lane in parallel across 4 rows (serial depth 2).
// Trilinear = per-lane w-lerp * weight, then xor-butterfly sum over the group.
__global__ __launch_bounds__(256) void deform4_kernel(
    const float* __restrict__ verts,
    const float* __restrict__ affine,
    const __half* __restrict__ packed,
    const float* __restrict__ invaff,
    float* __restrict__ out_pred,
    float* __restrict__ out_flow,
    int N, int B) {
    long t = (long)blockIdx.x * blockDim.x + threadIdx.x;
    long total = (long)B * N;
    long pt = t >> 2;
    int sub = (int)(t & 3);
    bool valid = pt < total;
    long i = valid ? pt : total - 1;
    int b = (int)(i / N);
    int n = (int)(i - (long)b * N);
    int hsel = sub & 1;          // h1 if set
    int dsel = (sub >> 1) & 1;   // d1 if set

    const float* A = affine + b * 16;
    const float* v = verts + (size_t)i * 3;
    float vx = v[0], vy = v[1], vz = v[2];
    float x = A[0] * vx + A[1] * vy + A[2]  * vz + A[3];
    float y = A[4] * vx + A[5] * vy + A[6]  * vz + A[7];
    float z = A[8] * vx + A[9] * vy + A[10] * vz + A[11];
    const float px = x, py = y, pz = z;

    const char* Pb = (const char*)(packed + (size_t)b * DHW * 4);
    const float scale = (float)(1.0 / NSTEPS);

    float cw0[3], cw1[3];   // own row's 3 channels at w0 / w1 (pre-scaled)
    int key = -1;

    for (int s = 0; s < NSTEPS; s++) {
        float pd = fminf(fmaxf(x, 0.0f), (float)(DIM - 1));
        float ph = fminf(fmaxf(y, 0.0f), (float)(DIM - 1));
        float pw = fminf(fmaxf(z, 0.0f), (float)(DIM - 1));
        float fd0 = floorf(pd), fh0 = floorf(ph), fw0 = floorf(pw);
        int d0 = (int)fd0, h0 = (int)fh0, w0 = (int)fw0;
        float fd = pd - fd0, fh = ph - fh0, fw = pw - fw0;

        int k = (d0 * DIM + h0) * DIM + w0;
        if (k != key) {            // uniform within the 4-lane group
            key = k;
            int d1 = min(d0 + 1, DIM - 1);
            int h1 = min(h0 + 1, DIM - 1);
            int dr = dsel ? d1 : d0;
            int hr = hsel ? h1 : h0;
            int lb = min(w0, DIM - 2);   // load voxel pair (lb, lb+1)
            int sel = w0 - lb;           // 1 only when w0==191 (fw==0 there)
            const uint2* p = reinterpret_cast<const uint2*>(
                Pb + (size_t)((dr * DIM + hr) * DIM + lb) * 8);
            uint2 qa = p[0];             // voxel lb:   (c0,c1),(c2,pad)
            uint2 qb = p[1];             // voxel lb+1: (c0,c1),(c2,pad)
            float2 a01 = h2f(qa.x), a2_ = h2f(qa.y);
            float2 b01 = h2f(qb.x), b2_ = h2f(qb.y);
            cw0[0] = (sel ? b01.x : a01.x) * scale;
            cw0[1] = (sel ? b01.y : a01.y) * scale;
            cw0[2] = (sel ? b2_.x : a2_.x) * scale;
            cw1[0] = b01.x * scale;
            cw1[1] = b01.y * scale;
            cw1[2] = b2_.x * scale;
        }

        float omfw = 1.0f - fw;
        float wgt = (hsel ? fh : 1.0f - fh) * (dsel ? fd : 1.0f - fd);
        float v0 = (cw0[0] * omfw + cw1[0] * fw) * wgt;
        float v1 = (cw0[1] * omfw + cw1[1] * fw) * wgt;
        float v2 = (cw0[2] * omfw + cw1[2] * fw) * wgt;
        // butterfly sum within aligned 4-lane group
        v0 += __shfl_xor(v0, 1, 64); v0 += __shfl_xor(v0, 2, 64);
        v1 += __shfl_xor(v1, 1, 64); v1 += __shfl_xor(v1, 2, 64);
        v2 += __shfl_xor(v2, 1, 64); v2 += __shfl_xor(v2, 2, 64);
        x += v0; y += v1; z += v2;
    }

    if (valid && sub < 3) {        // lane sub writes channel sub
        float posc = (sub == 0) ? x : (sub == 1) ? y : z;
        float p0c  = (sub == 0) ? px : (sub == 1) ? py : pz;
        float fint = posc - p0c;
        const float* Ai = invaff + b * 16 + sub * 4;
        float o = Ai[0] * x + Ai[1] * y + Ai[2] * z + Ai[3];
        out_pred[(size_t)i * 3 + sub] = o;                      // (B,N,3)
        out_flow[(size_t)b * 3 * N + (size_t)sub * N + n] = fint; // (B,3,N)
    }
}

// Fallback: f32 direct-gather (3 lanes/point) if ws can't hold the packed volume.
__global__ __launch_bounds__(256) void deform_kernel(
    const float* __restrict__ verts,
    const float* __restrict__ affine,
    const float* __restrict__ flow,
    const float* __restrict__ invaff,
    float* __restrict__ out_pred,
    float* __restrict__ out_flow,
    int N, int B) {
    int lane = threadIdx.x & 63;
    int wib  = threadIdx.x >> 6;
    long gwave = (long)blockIdx.x * (blockDim.x >> 6) + wib;
    int piw = lane / 3;
    if (piw > PTS_PER_WAVE - 1) piw = PTS_PER_WAVE - 1;
    int ch = lane - piw * 3;
    if (ch > 2) ch = 2;
    long pt = gwave * PTS_PER_WAVE + piw;
    bool valid = (lane < 63) && (pt < (long)B * N);
    long ptc = valid ? pt : ((long)B * N - 1);
    int b = (int)(ptc / N);
    int n = (int)(ptc - (long)b * N);
    const float* A = affine + b * 16;
    const float* v = verts + (size_t)ptc * 3;
    float vx = v[0], vy = v[1], vz = v[2];
    float x = A[0] * vx + A[1] * vy + A[2]  * vz + A[3];
    float y = A[4] * vx + A[5] * vy + A[6]  * vz + A[7];
    float z = A[8] * vx + A[9] * vy + A[10] * vz + A[11];
    float p0 = (ch == 0) ? x : (ch == 1) ? y : z;
    const float* Fc = flow + ((size_t)b * 3 + ch) * (size_t)DHW;
    const float scale = (float)(1.0 / NSTEPS);
    float cc[8];
    int key = -1;
    int bl = piw * 3;
    for (int s = 0; s < NSTEPS; s++) {
        float pd = fminf(fmaxf(x, 0.0f), (float)(DIM - 1));
        float ph = fminf(fmaxf(y, 0.0f), (float)(DIM - 1));
        float pw = fminf(fmaxf(z, 0.0f), (float)(DIM - 1));
        float fd0 = floorf(pd), fh0 = floorf(ph), fw0 = floorf(pw);
        int d0 = (int)fd0, h0 = (int)fh0, w0 = (int)fw0;
        float fd = pd - fd0, fh = ph - fh0, fw = pw - fw0;
        int k = (d0 * DIM + h0) * DIM + w0;
        if (k != key) {
            key = k;
            int d1 = min(d0 + 1, DIM - 1);
            int h1 = min(h0 + 1, DIM - 1);
            int w1 = min(w0 + 1, DIM - 1);
            int r00 = (d0 * DIM + h0) * DIM;
            int r01 = (d0 * DIM + h1) * DIM;
            int r10 = (d1 * DIM + h0) * DIM;
            int r11 = (d1 * DIM + h1) * DIM;
            cc[0] = Fc[r00 + w0] * scale;
            cc[1] = Fc[r00 + w1] * scale;
            cc[2] = Fc[r01 + w0] * scale;
            cc[3] = Fc[r01 + w1] * scale;
            cc[4] = Fc[r10 + w0] * scale;
            cc[5] = Fc[r10 + w1] * scale;
            cc[6] = Fc[r11 + w0] * scale;
            cc[7] = Fc[r11 + w1] * scale;
        }
        float omfw = 1.0f - fw, omfh = 1.0f - fh, omfd = 1.0f - fd;
        float c00 = cc[0] * omfw + cc[1] * fw;
        float c01 = cc[2] * omfw + cc[3] * fw;
        float c10 = cc[4] * omfw + cc[5] * fw;
        float c11 = cc[6] * omfw + cc[7] * fw;
        float c0 = c00 * omfh + c01 * fh;
        float c1 = c10 * omfh + c11 * fh;
        float val = c0 * omfd + c1 * fd;
        float v0 = __shfl(val, bl,     64);
        float v1 = __shfl(val, bl + 1, 64);
        float v2 = __shfl(val, bl + 2, 64);
        x += v0; y += v1; z += v2;
    }
    if (valid) {
        float posc = (ch == 0) ? x : (ch == 1) ? y : z;
        float fint = posc - p0;
        const float* Ai = invaff + b * 16 + ch * 4;
        float o = Ai[0] * x + Ai[1] * y + Ai[2] * z + Ai[3];
        out_pred[(size_t)ptc * 3 + ch] = o;
        out_flow[(size_t)b * 3 * N + (size_t)ch * N + n] = fint;
    }
}

extern "C" void kernel_launch(void* const* d_in, const int* in_sizes, int n_in,
                              void* d_out, int out_size, void* d_ws, size_t ws_size,
                              hipStream_t stream) {
    const float* verts  = (const float*)d_in[0];
    const float* affine = (const float*)d_in[1];
    const float* flow   = (const float*)d_in[2];

    int B = in_sizes[1] / 16;          // affine is B*4*4
    int N = in_sizes[0] / (3 * B);     // verts is B*N*3

    float* out_pred = (float*)d_out;                      // (B,N,3)
    float* out_flow = out_pred + (size_t)B * N * 3;       // (B,3,N)

    size_t packed_bytes = (size_t)B * DHW * 4 * sizeof(__half);  // 8B/voxel
    bool use_packed = (ws_size >= packed_bytes + 256);

    long total = (long)B * N;

    if (use_packed) {
        __half* packed = (__half*)d_ws;
        float* invaff  = (float*)((char*)d_ws + packed_bytes);
        hipLaunchKernelGGL(invert4x4_kernel, dim3(1), dim3(64), 0, stream,
                           affine, invaff, B);
        long quads = (DHW + 3) / 4;
        long vblocks = (quads + 255) / 256;
        hipLaunchKernelGGL(repack4_kernel, dim3((unsigned)vblocks, B), dim3(256), 0,
                           stream, flow, packed);
        long threads = total * 4;
        long blocks = (threads + 255) / 256;
        hipLaunchKernelGGL(deform4_kernel, dim3((unsigned)blocks), dim3(256), 0,
                           stream, verts, affine, packed, invaff,
                           out_pred, out_flow, N, B);
    } else {
        float* invaff = (float*)d_ws;
        hipLaunchKernelGGL(invert4x4_kernel, dim3(1), dim3(64), 0, stream,
                           affine, invaff, B);
        long waves  = (total + PTS_PER_WAVE - 1) / PTS_PER_WAVE;
        long blocks = (waves + 3) / 4;
        hipLaunchKernelGGL(deform_kernel, dim3((unsigned)blocks), dim3(256), 0,
                           stream, verts, affine, flow, invaff,
                           out_pred, out_flow, N, B);
    }
}